// Round 18
// baseline (2323.426 us; speedup 1.0000x reference)
//
#include <hip/hip_runtime.h>
#include <hip/hip_bf16.h>

#define B_ 64
#define T_ 256
#define EMB_ 512
#define HID_ 1024
#define G4_ 4096
#define NCLS_ 32000
#define BH (B_ * HID_)

typedef _Float16 f16;
typedef _Float16 f16x8 __attribute__((ext_vector_type(8)));
typedef _Float16 f16x4 __attribute__((ext_vector_type(4)));
typedef float f32x4 __attribute__((ext_vector_type(4)));
typedef unsigned long long u64;

__device__ __forceinline__ float sigm(float x) { return 1.f / (1.f + __expf(-x)); }

// LLC/fabric-coherent (cross-XCD) accessors (R3..R15-proven).
__device__ __forceinline__ void stg_u64(u64* p, u64 v) {
  __hip_atomic_store(p, v, __ATOMIC_RELAXED, __HIP_MEMORY_SCOPE_AGENT);
}
__device__ __forceinline__ unsigned ldg_u32(const unsigned* p) {
  return __hip_atomic_load(p, __ATOMIC_RELAXED, __HIP_MEMORY_SCOPE_AGENT);
}
__device__ __forceinline__ void fadd_u32(unsigned* p) {
  __hip_atomic_fetch_add(p, 1u, __ATOMIC_RELAXED, __HIP_MEMORY_SCOPE_AGENT);
}

// ---------------- prep kernels ----------------

__global__ __launch_bounds__(256) void cvt_kernel(const float* __restrict__ src,
                                                  f16* __restrict__ dst, int n4) {
  int i = blockIdx.x * 256 + threadIdx.x;
  if (i < n4) {
    float4 v = ((const float4*)src)[i];
    f16x4 o = {(f16)v.x, (f16)v.y, (f16)v.z, (f16)v.w};
    *(f16x4*)(dst + (size_t)i * 4) = o;
  }
}

__global__ __launch_bounds__(256) void bsum_kernel(const float* __restrict__ a0,
                                                   const float* __restrict__ b0,
                                                   float* __restrict__ o0,
                                                   const float* __restrict__ a1,
                                                   const float* __restrict__ b1,
                                                   float* __restrict__ o1) {
  int i = blockIdx.x * 256 + threadIdx.x;
  if (i < G4_) {
    o0[i] = a0[i] + b0[i];
    o1[i] = a1[i] + b1[i];
  }
}

// x0 layout: [T][B][EMB] fp16 (row-major; cached, not on exchange path)
__global__ __launch_bounds__(128) void gather_kernel(const int* __restrict__ tokens,
                                                     const float* __restrict__ emb,
                                                     f16* __restrict__ x0) {
  int blk = blockIdx.x;  // t*64 + b
  int t = blk >> 6, b = blk & 63;
  int tok = tokens[b * T_ + t];
  float4 v = ((const float4*)(emb + (size_t)tok * EMB_))[threadIdx.x];
  f16x4 o = {(f16)v.x, (f16)v.y, (f16)v.z, (f16)v.w};
  *(f16x4*)(x0 + (size_t)blk * EMB_ + threadIdx.x * 4) = o;
}

// ---------------- fused persistent recurrence kernel ----------------
// R15 skeleton (passing, 1821us; R16/R17 variants both regressed and are
// reverted). ONE change vs R15: CONCURRENT counter preloads. At step start
// each wave issues all its sector-counter loads back-to-back (layer0: 2,
// hidden under the x-part KPH; layer1: 4, one concurrent RTT instead of 4
// serial). WAITS2 checks the preloaded value first and only polls if stale.
// No duplicated KPHB bodies (R16's poison), barrier D intact (R17's poison).
#define KPH(AP, ASTR, WCOL0, ACOL0, N)                                          \
  _Pragma("unroll") for (int f = 0; f < (N); ++f) {                             \
    const f16* ap0 = (AP) + (size_t)r0 * (ASTR) + ((ACOL0) + f) * 32 + lk * 8;  \
    const f16* ap1 = (AP) + (size_t)r1 * (ASTR) + ((ACOL0) + f) * 32 + lk * 8;  \
    f16x8 a0 = *(const f16x8*)ap0;                                              \
    f16x8 a1 = *(const f16x8*)ap1;                                              \
    f16x8 b0 = *(const f16x8*)(wr0 + ((WCOL0) + f) * 32);                       \
    f16x8 b1 = *(const f16x8*)(wr1 + ((WCOL0) + f) * 32);                       \
    acc00 = __builtin_amdgcn_mfma_f32_16x16x32_f16(a0, b0, acc00, 0, 0, 0);     \
    acc01 = __builtin_amdgcn_mfma_f32_16x16x32_f16(a0, b1, acc01, 0, 0, 0);     \
    acc10 = __builtin_amdgcn_mfma_f32_16x16x32_f16(a1, b0, acc10, 0, 0, 0);     \
    acc11 = __builtin_amdgcn_mfma_f32_16x16x32_f16(a1, b1, acc11, 0, 0, 0);     \
  }

#define KPHB(AP, WCOL0, AG0, N)                                                 \
  _Pragma("unroll") for (int f = 0; f < (N); ++f) {                             \
    const f16* ap0 = (AP) + (((AG0) + f) * 4 + lk) * 512 + r0 * 8;              \
    const f16* ap1 = (AP) + (((AG0) + f) * 4 + lk) * 512 + r1 * 8;              \
    f16x8 a0 = *(const f16x8*)ap0;                                              \
    f16x8 a1 = *(const f16x8*)ap1;                                              \
    f16x8 b0 = *(const f16x8*)(wr0 + ((WCOL0) + f) * 32);                       \
    f16x8 b1 = *(const f16x8*)(wr1 + ((WCOL0) + f) * 32);                       \
    acc00 = __builtin_amdgcn_mfma_f32_16x16x32_f16(a0, b0, acc00, 0, 0, 0);     \
    acc01 = __builtin_amdgcn_mfma_f32_16x16x32_f16(a0, b1, acc01, 0, 0, 0);     \
    acc10 = __builtin_amdgcn_mfma_f32_16x16x32_f16(a1, b0, acc10, 0, 0, 0);     \
    acc11 = __builtin_amdgcn_mfma_f32_16x16x32_f16(a1, b1, acc11, 0, 0, 0);     \
  }

// sector wait with preloaded initial value: zero extra RTT when satisfied
#define WAITS2(ADDR, TGT, VINIT)                                            \
  {                                                                         \
    const unsigned tg_ = (TGT);                                             \
    unsigned v_ = (VINIT);                                                  \
    int it_ = 0;                                                            \
    while (v_ < tg_) {                                                      \
      if (++it_ > 4000000) break; /* safety valve: degrade, don't hang */   \
      v_ = ldg_u32(ADDR);                                                   \
      if (v_ >= tg_) break;                                                 \
      __builtin_amdgcn_s_sleep(2);                                          \
    }                                                                       \
  }

__global__ __launch_bounds__(512, 2) void persist_kernel(
    const f16* __restrict__ x0, const f16* __restrict__ w0i,
    const f16* __restrict__ w0h, const f16* __restrict__ w1i,
    const f16* __restrict__ w1h, const float* __restrict__ b0s,
    const float* __restrict__ b1s, f16* __restrict__ h0r,
    f16* __restrict__ h1r, unsigned* flags) {
  __shared__ f16 Ws[32 * 2056];       // 131584 B: 32 rows x (Kcat + 8 pad)
  __shared__ float red[6 * 64 * 17];  // 26112 B: K-partials; reused as pre[32][68]
  __shared__ float cst[512];          // 2 KB cell state [b][u]

  const int layer = blockIdx.x >> 7;
  const int slice = blockIdx.x & 127;
  const int sector = slice >> 4;      // contiguous: units sector*128..+127
  const int tid = threadIdx.x;
  const int lane = tid & 63, wave = tid >> 6;
  const int mi = wave >> 2, kq = wave & 3;
  const int lr = lane & 15, lk = lane >> 4;
  const int j0 = slice * 8;

  const f16* whh = layer ? w1h : w0h;
  const f16* wih = layer ? w1i : w0i;
  const float* bs = layer ? b1s : b0s;
  f16* hown = layer ? h1r : h0r;
  const int KI = layer ? HID_ : EMB_;
  const int nch = (HID_ + KI) >> 3;   // uint4 chunks per row
  const int wstr = HID_ + KI + 8;     // 2056 / 1544

  unsigned* ctr_own = flags + (layer ? 256 : 0);
  unsigned* ctr_l0 = flags;
  unsigned* ca0 = ctr_own + (kq * 2) * 32;      // own-chain sector lines
  unsigned* ca1 = ctr_own + (kq * 2 + 1) * 32;
  unsigned* cq0 = ctr_l0 + (kq * 2) * 32;       // chain0 sector lines (layer1)
  unsigned* cq1 = ctr_l0 + (kq * 2 + 1) * 32;

  // ---- one-time: stage Wcat = [W_hh | W_ih] rows into LDS (R6-proven) ----
  for (int r = wave * 4; r < wave * 4 + 4; ++r) {
    int grow = (r >> 3) * HID_ + j0 + (r & 7);  // gate*HID + unit
    for (int c = lane; c < nch; c += 64) {
      int kk = c * 8;
      const f16* src = (kk < HID_) ? (whh + (size_t)grow * HID_ + kk)
                                   : (wih + (size_t)grow * KI + (kk - HID_));
      *(uint4*)(Ws + r * wstr + kk) = *(const uint4*)src;
    }
  }
  float brg[4][4];
  {
    int u4 = (tid & 1) * 4;
#pragma unroll
    for (int g = 0; g < 4; ++g)
#pragma unroll
      for (int e = 0; e < 4; ++e) brg[g][e] = bs[g * HID_ + j0 + u4 + e];
  }
  for (int i = tid; i < 512; i += 512) cst[i] = 0.f;
  __syncthreads();

  const int r0 = mi * 32 + lr, r1 = r0 + 16;
  const f16* wr0 = Ws + lr * wstr + lk * 8;
  const f16* wr1 = wr0 + 16 * wstr;

  for (int s = 0; s < T_; ++s) {
    f32x4 acc00 = {}, acc01 = {}, acc10 = {}, acc11 = {};

    if (layer == 0) {
      const unsigned tgo = 16u * (unsigned)s;
      // ---- preload own-chain counters (RTT hides under x-part) ----
      unsigned p0 = ldg_u32(ca0);
      unsigned p1 = ldg_u32(ca1);
      // ---- x-part (no dependency) ----
      const f16* xb = x0 + (size_t)s * (B_ * EMB_);
      KPH(xb, EMB_, 32 + kq * 4, kq * 4, 4)
      // ---- h-part: sector-pipelined (wave kq owns sectors 2kq, 2kq+1) ----
      const f16* hb = h0r + (size_t)s * BH;  // h0[s-1] in slot s
      WAITS2(ca0, tgo, p0)
      KPHB(hb, (kq * 2) * 4, (kq * 2) * 4, 4)
      WAITS2(ca1, tgo, p1)
      KPHB(hb, (kq * 2 + 1) * 4, (kq * 2 + 1) * 4, 4)
    } else {
      const unsigned tgl0 = 16u * (unsigned)(s + 1);
      const unsigned tgo = 16u * (unsigned)s;
      // ---- preload all 4 counters: one concurrent RTT ----
      unsigned q0 = ldg_u32(cq0);
      unsigned q1 = ldg_u32(cq1);
      unsigned p0 = ldg_u32(ca0);
      unsigned p1 = ldg_u32(ca1);
      // ---- x-part = h0[s] (slot s+1): sector-pipelined vs chain0 ----
      const f16* xb = h0r + (size_t)(s + 1) * BH;
      WAITS2(cq0, tgl0, q0)
      KPHB(xb, 32 + (kq * 2) * 4, (kq * 2) * 4, 4)
      WAITS2(cq1, tgl0, q1)
      KPHB(xb, 32 + (kq * 2 + 1) * 4, (kq * 2 + 1) * 4, 4)
      // ---- h-part: sector-pipelined vs own chain ----
      const f16* hb = h1r + (size_t)s * BH;
      WAITS2(ca0, tgo, p0)
      KPHB(hb, (kq * 2) * 4, (kq * 2) * 4, 4)
      WAITS2(ca1, tgo, p1)
      KPHB(hb, (kq * 2 + 1) * 4, (kq * 2 + 1) * 4, 4)
    }

    // ---- K-reduce: kq 1..3 publish (17-f32 lane stride, conflict-free) ----
    if (kq) {
      float* rp = red + ((mi * 3 + kq - 1) * 64 + lane) * 17;
      *(f32x4*)(rp) = acc00;      *(f32x4*)(rp + 4) = acc01;
      *(f32x4*)(rp + 8) = acc10;  *(f32x4*)(rp + 12) = acc11;
    }
    __syncthreads();  // A: partials visible
    if (!kq) {
#pragma unroll
      for (int q = 0; q < 3; ++q) {
        const float* rp = red + ((mi * 3 + q) * 64 + lane) * 17;
        acc00 += *(const f32x4*)(rp);      acc01 += *(const f32x4*)(rp + 4);
        acc10 += *(const f32x4*)(rp + 8);  acc11 += *(const f32x4*)(rp + 12);
      }
    }
    __syncthreads();  // B: red reads done before pre overwrites red
    if (!kq) {
      float* pre = red;  // union
      int col = mi * 32 + lk * 4;
      *(f32x4*)(pre + (0 + lr) * 68 + col) = acc00;
      *(f32x4*)(pre + (16 + lr) * 68 + col) = acc01;
      *(f32x4*)(pre + (0 + lr) * 68 + col + 16) = acc10;
      *(f32x4*)(pre + (16 + lr) * 68 + col + 16) = acc11;
    }
    __syncthreads();  // C: pre ready

    // ---- LSTM elementwise: 128 threads x (1 batch, 4 units) -> 8B store ----
    if (tid < 128) {
      const float* pre = red;
      f16* hout = hown + (size_t)(s + 1) * BH;  // blocked slot base
      int b = tid >> 1, u4 = (tid & 1) * 4;
      f16x4 hv;
#pragma unroll
      for (int e = 0; e < 4; ++e) {
        int r = u4 + e;
        float pi = pre[(0 * 8 + r) * 68 + b] + brg[0][e];
        float pf = pre[(1 * 8 + r) * 68 + b] + brg[1][e];
        float pg = pre[(2 * 8 + r) * 68 + b] + brg[2][e];
        float po = pre[(3 * 8 + r) * 68 + b] + brg[3][e];
        float ig = sigm(pi), fg = sigm(pf), gg = tanhf(pg), og = sigm(po);
        float cn = fg * cst[b * 8 + r] + ig * gg;
        cst[b * 8 + r] = cn;
        hv[e] = (f16)(og * tanhf(cn));
      }
      stg_u64((u64*)(hout + slice * 512 + b * 8 + u4),
              __builtin_bit_cast(u64, hv));
    }

    // ---- publish: drain h stores, then arrival add on own contiguous sector ----
    asm volatile("s_waitcnt vmcnt(0)" ::: "memory");
    __syncthreads();  // D: h stores drained, pre reads done
    if (tid == 0) fadd_u32(&ctr_own[sector * 32]);
  }
}

// ---------------- FC kernel: out = h1_last @ fc_w^T + fc_b ----------------
// A (h1[256]) is in blocked layout: (b, k) at ((k>>3)*64 + b)*8 + (k&7).
__global__ __launch_bounds__(256) void fc_kernel(const f16* __restrict__ A,
                                                 const float* __restrict__ fcw,
                                                 const float* __restrict__ fcb,
                                                 float* __restrict__ out) {
  const int n0 = blockIdx.x * 64;
  __shared__ char smem[18432];
  f16* As = (f16*)smem;
  f16* Bs = (f16*)(smem + 9216);
  const int tid = threadIdx.x;
  const int lane = tid & 63, wave = tid >> 6;
  const int wm = wave & 1, wn = wave >> 1;
  const int lr = lane & 15, lk = lane >> 4;
  f32x4 acc[2][2] = {};

  for (int kt = 0; kt < HID_ / 64; ++kt) {
    const int k0 = kt * 64;
    __syncthreads();
#pragma unroll
    for (int i = 0; i < 2; ++i) {
      int id = tid + 256 * i;
      int r = id >> 3, c8 = id & 7;
      uint4 av = *(const uint4*)(A + (size_t)((k0 >> 3) + c8) * 512 + r * 8);
      *(uint4*)(As + r * 72 + c8 * 8) = av;
    }
#pragma unroll
    for (int i = 0; i < 4; ++i) {
      int id = tid + 256 * i;
      int r = id >> 4, c4 = id & 15;
      float4 v = *(const float4*)(fcw + (size_t)(n0 + r) * HID_ + k0 + c4 * 4);
      f16x4 o = {(f16)v.x, (f16)v.y, (f16)v.z, (f16)v.w};
      *(f16x4*)(Bs + r * 72 + c4 * 4) = o;
    }
    __syncthreads();
#pragma unroll
    for (int ks = 0; ks < 2; ++ks) {
      f16x8 a0 = *(const f16x8*)(As + (wm * 32 + lr) * 72 + ks * 32 + lk * 8);
      f16x8 a1 = *(const f16x8*)(As + (wm * 32 + 16 + lr) * 72 + ks * 32 + lk * 8);
      f16x8 b0 = *(const f16x8*)(Bs + (wn * 32 + lr) * 72 + ks * 32 + lk * 8);
      f16x8 b1 = *(const f16x8*)(Bs + (wn * 32 + 16 + lr) * 72 + ks * 32 + lk * 8);
      acc[0][0] = __builtin_amdgcn_mfma_f32_16x16x32_f16(a0, b0, acc[0][0], 0, 0, 0);
      acc[0][1] = __builtin_amdgcn_mfma_f32_16x16x32_f16(a0, b1, acc[0][1], 0, 0, 0);
      acc[1][0] = __builtin_amdgcn_mfma_f32_16x16x32_f16(a1, b0, acc[1][0], 0, 0, 0);
      acc[1][1] = __builtin_amdgcn_mfma_f32_16x16x32_f16(a1, b1, acc[1][1], 0, 0, 0);
    }
  }

#pragma unroll
  for (int mf = 0; mf < 2; ++mf)
#pragma unroll
    for (int nf = 0; nf < 2; ++nf) {
      int n = n0 + wn * 32 + nf * 16 + lr;
      float bias = fcb[n];
      int bbase = wm * 32 + mf * 16 + lk * 4;
#pragma unroll
      for (int rg = 0; rg < 4; ++rg)
        out[(size_t)(bbase + rg) * NCLS_ + n] = acc[mf][nf][rg] + bias;
    }
}

// ---------------- launch ----------------

extern "C" void kernel_launch(void* const* d_in, const int* in_sizes, int n_in,
                              void* d_out, int out_size, void* d_ws,
                              size_t ws_size, hipStream_t stream) {
  const int* tokens = (const int*)d_in[0];
  const float* emb = (const float*)d_in[1];
  const float* W_ih0 = (const float*)d_in[2];
  const float* W_hh0 = (const float*)d_in[3];
  const float* b_ih0 = (const float*)d_in[4];
  const float* b_hh0 = (const float*)d_in[5];
  const float* W_ih1 = (const float*)d_in[6];
  const float* W_hh1 = (const float*)d_in[7];
  const float* b_ih1 = (const float*)d_in[8];
  const float* b_hh1 = (const float*)d_in[9];
  const float* fc_w = (const float*)d_in[10];
  const float* fc_b = (const float*)d_in[11];
  float* out = (float*)d_out;

  char* ws = (char*)d_ws;
  size_t off = 0;
  auto carve = [&](size_t bytes) -> char* {
    char* p = ws + off;
    off += (bytes + 255) & ~(size_t)255;
    return p;
  };
  f16* w0i = (f16*)carve((size_t)G4_ * EMB_ * 2);
  f16* w0h = (f16*)carve((size_t)G4_ * HID_ * 2);
  f16* w1i = (f16*)carve((size_t)G4_ * HID_ * 2);
  f16* w1h = (f16*)carve((size_t)G4_ * HID_ * 2);
  f16* x0 = (f16*)carve((size_t)T_ * B_ * EMB_ * 2);
  float* b0s = (float*)carve(G4_ * 4);
  float* b1s = (float*)carve(G4_ * 4);
  f16* h0r = (f16*)carve(257ull * BH * 2);  // blocked: [t][slice][b][u8]
  f16* h1r = (f16*)carve(257ull * BH * 2);
  unsigned* flags = (unsigned*)carve(1024 * 4);  // 2 chains x 8 contiguous sectors

  hipMemsetAsync(flags, 0, 1024 * 4, stream);
  hipMemsetAsync(h0r, 0, (size_t)BH * 2, stream);
  hipMemsetAsync(h1r, 0, (size_t)BH * 2, stream);

  cvt_kernel<<<(G4_ * EMB_ / 4 + 255) / 256, 256, 0, stream>>>(W_ih0, w0i, G4_ * EMB_ / 4);
  cvt_kernel<<<(G4_ * HID_ / 4 + 255) / 256, 256, 0, stream>>>(W_hh0, w0h, G4_ * HID_ / 4);
  cvt_kernel<<<(G4_ * HID_ / 4 + 255) / 256, 256, 0, stream>>>(W_ih1, w1i, G4_ * HID_ / 4);
  cvt_kernel<<<(G4_ * HID_ / 4 + 255) / 256, 256, 0, stream>>>(W_hh1, w1h, G4_ * HID_ / 4);
  bsum_kernel<<<(G4_ + 255) / 256, 256, 0, stream>>>(b_ih0, b_hh0, b0s, b_ih1, b_hh1, b1s);
  gather_kernel<<<T_ * B_, 128, 0, stream>>>(tokens, emb, x0);

  persist_kernel<<<256, 512, 0, stream>>>(x0, w0i, w0h, w1i, w1h, b0s, b1s,
                                          h0r, h1r, flags);

  fc_kernel<<<NCLS_ / 64, 256, 0, stream>>>(h1r + 256ull * BH, fc_w, fc_b, out);
}

// Round 19
// 1827.953 us; speedup vs baseline: 1.2711x; 1.2711x over previous
//
#include <hip/hip_runtime.h>
#include <hip/hip_bf16.h>

#define B_ 64
#define T_ 256
#define EMB_ 512
#define HID_ 1024
#define G4_ 4096
#define NCLS_ 32000
#define BH (B_ * HID_)

typedef _Float16 f16;
typedef _Float16 f16x8 __attribute__((ext_vector_type(8)));
typedef _Float16 f16x4 __attribute__((ext_vector_type(4)));
typedef float f32x4 __attribute__((ext_vector_type(4)));
typedef unsigned long long u64;

__device__ __forceinline__ float sigm(float x) { return 1.f / (1.f + __expf(-x)); }

// LLC/fabric-coherent (cross-XCD) accessors (R3..R15-proven).
__device__ __forceinline__ void stg_u64(u64* p, u64 v) {
  __hip_atomic_store(p, v, __ATOMIC_RELAXED, __HIP_MEMORY_SCOPE_AGENT);
}
__device__ __forceinline__ unsigned ldg_u32(const unsigned* p) {
  return __hip_atomic_load(p, __ATOMIC_RELAXED, __HIP_MEMORY_SCOPE_AGENT);
}
__device__ __forceinline__ void fadd_u32(unsigned* p) {
  __hip_atomic_fetch_add(p, 1u, __ATOMIC_RELAXED, __HIP_MEMORY_SCOPE_AGENT);
}

// ---------------- prep kernels ----------------

__global__ __launch_bounds__(256) void cvt_kernel(const float* __restrict__ src,
                                                  f16* __restrict__ dst, int n4) {
  int i = blockIdx.x * 256 + threadIdx.x;
  if (i < n4) {
    float4 v = ((const float4*)src)[i];
    f16x4 o = {(f16)v.x, (f16)v.y, (f16)v.z, (f16)v.w};
    *(f16x4*)(dst + (size_t)i * 4) = o;
  }
}

__global__ __launch_bounds__(256) void bsum_kernel(const float* __restrict__ a0,
                                                   const float* __restrict__ b0,
                                                   float* __restrict__ o0,
                                                   const float* __restrict__ a1,
                                                   const float* __restrict__ b1,
                                                   float* __restrict__ o1) {
  int i = blockIdx.x * 256 + threadIdx.x;
  if (i < G4_) {
    o0[i] = a0[i] + b0[i];
    o1[i] = a1[i] + b1[i];
  }
}

// x0 layout: [T][B][EMB] fp16 (row-major; cached, not on exchange path)
__global__ __launch_bounds__(128) void gather_kernel(const int* __restrict__ tokens,
                                                     const float* __restrict__ emb,
                                                     f16* __restrict__ x0) {
  int blk = blockIdx.x;  // t*64 + b
  int t = blk >> 6, b = blk & 63;
  int tok = tokens[b * T_ + t];
  float4 v = ((const float4*)(emb + (size_t)tok * EMB_))[threadIdx.x];
  f16x4 o = {(f16)v.x, (f16)v.y, (f16)v.z, (f16)v.w};
  *(f16x4*)(x0 + (size_t)blk * EMB_ + threadIdx.x * 4) = o;
}

// ---------------- fused persistent recurrence kernel (R15 final) ----------
// Best configuration found (1834 us total; R16/R17/R18 one-change probes all
// regressed). Structure: fused gates = [W_hh|W_ih]x[h;x] (no xg intermediate),
// weights LDS-resident, h rings depth-257 single-assignment in slice-blocked
// layout (coalesced agent-scope exchange), two decoupled layer chains with
// contiguous-sector arrival counters and per-wave sector-pipelined waits.
#define KPH(AP, ASTR, WCOL0, ACOL0, N)                                          \
  _Pragma("unroll") for (int f = 0; f < (N); ++f) {                             \
    const f16* ap0 = (AP) + (size_t)r0 * (ASTR) + ((ACOL0) + f) * 32 + lk * 8;  \
    const f16* ap1 = (AP) + (size_t)r1 * (ASTR) + ((ACOL0) + f) * 32 + lk * 8;  \
    f16x8 a0 = *(const f16x8*)ap0;                                              \
    f16x8 a1 = *(const f16x8*)ap1;                                              \
    f16x8 b0 = *(const f16x8*)(wr0 + ((WCOL0) + f) * 32);                       \
    f16x8 b1 = *(const f16x8*)(wr1 + ((WCOL0) + f) * 32);                       \
    acc00 = __builtin_amdgcn_mfma_f32_16x16x32_f16(a0, b0, acc00, 0, 0, 0);     \
    acc01 = __builtin_amdgcn_mfma_f32_16x16x32_f16(a0, b1, acc01, 0, 0, 0);     \
    acc10 = __builtin_amdgcn_mfma_f32_16x16x32_f16(a1, b0, acc10, 0, 0, 0);     \
    acc11 = __builtin_amdgcn_mfma_f32_16x16x32_f16(a1, b1, acc11, 0, 0, 0);     \
  }

#define KPHB(AP, WCOL0, AG0, N)                                                 \
  _Pragma("unroll") for (int f = 0; f < (N); ++f) {                             \
    const f16* ap0 = (AP) + (((AG0) + f) * 4 + lk) * 512 + r0 * 8;              \
    const f16* ap1 = (AP) + (((AG0) + f) * 4 + lk) * 512 + r1 * 8;              \
    f16x8 a0 = *(const f16x8*)ap0;                                              \
    f16x8 a1 = *(const f16x8*)ap1;                                              \
    f16x8 b0 = *(const f16x8*)(wr0 + ((WCOL0) + f) * 32);                       \
    f16x8 b1 = *(const f16x8*)(wr1 + ((WCOL0) + f) * 32);                       \
    acc00 = __builtin_amdgcn_mfma_f32_16x16x32_f16(a0, b0, acc00, 0, 0, 0);     \
    acc01 = __builtin_amdgcn_mfma_f32_16x16x32_f16(a0, b1, acc01, 0, 0, 0);     \
    acc10 = __builtin_amdgcn_mfma_f32_16x16x32_f16(a1, b0, acc10, 0, 0, 0);     \
    acc11 = __builtin_amdgcn_mfma_f32_16x16x32_f16(a1, b1, acc11, 0, 0, 0);     \
  }

// per-wave sector wait: all lanes load the SAME line (1 transaction/poll)
#define WAITS(ADDR, TGT)                                                    \
  {                                                                         \
    const unsigned tg_ = (TGT);                                             \
    unsigned v_ = ldg_u32(ADDR);                                            \
    int it_ = 0;                                                            \
    while (v_ < tg_) {                                                      \
      if (++it_ > 4000000) break; /* safety valve: degrade, don't hang */   \
      __builtin_amdgcn_s_sleep(2);                                          \
      v_ = ldg_u32(ADDR);                                                   \
    }                                                                       \
  }

__global__ __launch_bounds__(512, 2) void persist_kernel(
    const f16* __restrict__ x0, const f16* __restrict__ w0i,
    const f16* __restrict__ w0h, const f16* __restrict__ w1i,
    const f16* __restrict__ w1h, const float* __restrict__ b0s,
    const float* __restrict__ b1s, f16* __restrict__ h0r,
    f16* __restrict__ h1r, unsigned* flags) {
  __shared__ f16 Ws[32 * 2056];       // 131584 B: 32 rows x (Kcat + 8 pad)
  __shared__ float red[6 * 64 * 17];  // 26112 B: K-partials; reused as pre[32][68]
  __shared__ float cst[512];          // 2 KB cell state [b][u]

  const int layer = blockIdx.x >> 7;
  const int slice = blockIdx.x & 127;
  const int sector = slice >> 4;      // contiguous: units sector*128..+127
  const int tid = threadIdx.x;
  const int lane = tid & 63, wave = tid >> 6;
  const int mi = wave >> 2, kq = wave & 3;
  const int lr = lane & 15, lk = lane >> 4;
  const int j0 = slice * 8;

  const f16* whh = layer ? w1h : w0h;
  const f16* wih = layer ? w1i : w0i;
  const float* bs = layer ? b1s : b0s;
  f16* hown = layer ? h1r : h0r;
  const int KI = layer ? HID_ : EMB_;
  const int nch = (HID_ + KI) >> 3;   // uint4 chunks per row
  const int wstr = HID_ + KI + 8;     // 2056 / 1544

  unsigned* ctr_own = flags + (layer ? 256 : 0);
  unsigned* ctr_l0 = flags;

  // ---- one-time: stage Wcat = [W_hh | W_ih] rows into LDS (R6-proven) ----
  for (int r = wave * 4; r < wave * 4 + 4; ++r) {
    int grow = (r >> 3) * HID_ + j0 + (r & 7);  // gate*HID + unit
    for (int c = lane; c < nch; c += 64) {
      int kk = c * 8;
      const f16* src = (kk < HID_) ? (whh + (size_t)grow * HID_ + kk)
                                   : (wih + (size_t)grow * KI + (kk - HID_));
      *(uint4*)(Ws + r * wstr + kk) = *(const uint4*)src;
    }
  }
  float brg[4][4];
  {
    int u4 = (tid & 1) * 4;
#pragma unroll
    for (int g = 0; g < 4; ++g)
#pragma unroll
      for (int e = 0; e < 4; ++e) brg[g][e] = bs[g * HID_ + j0 + u4 + e];
  }
  for (int i = tid; i < 512; i += 512) cst[i] = 0.f;
  __syncthreads();

  const int r0 = mi * 32 + lr, r1 = r0 + 16;
  const f16* wr0 = Ws + lr * wstr + lk * 8;
  const f16* wr1 = wr0 + 16 * wstr;

  for (int s = 0; s < T_; ++s) {
    f32x4 acc00 = {}, acc01 = {}, acc10 = {}, acc11 = {};

    if (layer == 0) {
      // ---- x-part (no dependency) ----
      const f16* xb = x0 + (size_t)s * (B_ * EMB_);
      KPH(xb, EMB_, 32 + kq * 4, kq * 4, 4)
      // ---- h-part: sector-pipelined (wave kq owns sectors 2kq, 2kq+1) ----
      const f16* hb = h0r + (size_t)s * BH;  // h0[s-1] in slot s
#pragma unroll
      for (int sq = 0; sq < 2; ++sq) {
        int sec = kq * 2 + sq;
        WAITS(ctr_own + sec * 32, 16u * (unsigned)s)
        KPHB(hb, sec * 4, sec * 4, 4)
      }
    } else {
      // ---- x-part = h0[s] (slot s+1): sector-pipelined vs chain0 ----
      const f16* xb = h0r + (size_t)(s + 1) * BH;
#pragma unroll
      for (int sq = 0; sq < 2; ++sq) {
        int sec = kq * 2 + sq;
        WAITS(ctr_l0 + sec * 32, 16u * (unsigned)(s + 1))
        KPHB(xb, 32 + sec * 4, sec * 4, 4)
      }
      // ---- h-part: sector-pipelined vs own chain ----
      const f16* hb = h1r + (size_t)s * BH;
#pragma unroll
      for (int sq = 0; sq < 2; ++sq) {
        int sec = kq * 2 + sq;
        WAITS(ctr_own + sec * 32, 16u * (unsigned)s)
        KPHB(hb, sec * 4, sec * 4, 4)
      }
    }

    // ---- K-reduce: kq 1..3 publish (17-f32 lane stride, conflict-free) ----
    if (kq) {
      float* rp = red + ((mi * 3 + kq - 1) * 64 + lane) * 17;
      *(f32x4*)(rp) = acc00;      *(f32x4*)(rp + 4) = acc01;
      *(f32x4*)(rp + 8) = acc10;  *(f32x4*)(rp + 12) = acc11;
    }
    __syncthreads();  // A: partials visible
    if (!kq) {
#pragma unroll
      for (int q = 0; q < 3; ++q) {
        const float* rp = red + ((mi * 3 + q) * 64 + lane) * 17;
        acc00 += *(const f32x4*)(rp);      acc01 += *(const f32x4*)(rp + 4);
        acc10 += *(const f32x4*)(rp + 8);  acc11 += *(const f32x4*)(rp + 12);
      }
    }
    __syncthreads();  // B: red reads done before pre overwrites red
    if (!kq) {
      float* pre = red;  // union
      int col = mi * 32 + lk * 4;
      *(f32x4*)(pre + (0 + lr) * 68 + col) = acc00;
      *(f32x4*)(pre + (16 + lr) * 68 + col) = acc01;
      *(f32x4*)(pre + (0 + lr) * 68 + col + 16) = acc10;
      *(f32x4*)(pre + (16 + lr) * 68 + col + 16) = acc11;
    }
    __syncthreads();  // C: pre ready

    // ---- LSTM elementwise: 128 threads x (1 batch, 4 units) -> 8B store ----
    if (tid < 128) {
      const float* pre = red;
      f16* hout = hown + (size_t)(s + 1) * BH;  // blocked slot base
      int b = tid >> 1, u4 = (tid & 1) * 4;
      f16x4 hv;
#pragma unroll
      for (int e = 0; e < 4; ++e) {
        int r = u4 + e;
        float pi = pre[(0 * 8 + r) * 68 + b] + brg[0][e];
        float pf = pre[(1 * 8 + r) * 68 + b] + brg[1][e];
        float pg = pre[(2 * 8 + r) * 68 + b] + brg[2][e];
        float po = pre[(3 * 8 + r) * 68 + b] + brg[3][e];
        float ig = sigm(pi), fg = sigm(pf), gg = tanhf(pg), og = sigm(po);
        float cn = fg * cst[b * 8 + r] + ig * gg;
        cst[b * 8 + r] = cn;
        hv[e] = (f16)(og * tanhf(cn));
      }
      stg_u64((u64*)(hout + slice * 512 + b * 8 + u4),
              __builtin_bit_cast(u64, hv));
    }

    // ---- publish: drain h stores, then arrival add on own contiguous sector ----
    asm volatile("s_waitcnt vmcnt(0)" ::: "memory");
    __syncthreads();  // D: h stores drained, pre reads done
    if (tid == 0) fadd_u32(&ctr_own[sector * 32]);
  }
}

// ---------------- FC kernel: out = h1_last @ fc_w^T + fc_b ----------------
// A (h1[256]) is in blocked layout: (b, k) at ((k>>3)*64 + b)*8 + (k&7).
__global__ __launch_bounds__(256) void fc_kernel(const f16* __restrict__ A,
                                                 const float* __restrict__ fcw,
                                                 const float* __restrict__ fcb,
                                                 float* __restrict__ out) {
  const int n0 = blockIdx.x * 64;
  __shared__ char smem[18432];
  f16* As = (f16*)smem;
  f16* Bs = (f16*)(smem + 9216);
  const int tid = threadIdx.x;
  const int lane = tid & 63, wave = tid >> 6;
  const int wm = wave & 1, wn = wave >> 1;
  const int lr = lane & 15, lk = lane >> 4;
  f32x4 acc[2][2] = {};

  for (int kt = 0; kt < HID_ / 64; ++kt) {
    const int k0 = kt * 64;
    __syncthreads();
#pragma unroll
    for (int i = 0; i < 2; ++i) {
      int id = tid + 256 * i;
      int r = id >> 3, c8 = id & 7;
      uint4 av = *(const uint4*)(A + (size_t)((k0 >> 3) + c8) * 512 + r * 8);
      *(uint4*)(As + r * 72 + c8 * 8) = av;
    }
#pragma unroll
    for (int i = 0; i < 4; ++i) {
      int id = tid + 256 * i;
      int r = id >> 4, c4 = id & 15;
      float4 v = *(const float4*)(fcw + (size_t)(n0 + r) * HID_ + k0 + c4 * 4);
      f16x4 o = {(f16)v.x, (f16)v.y, (f16)v.z, (f16)v.w};
      *(f16x4*)(Bs + r * 72 + c4 * 4) = o;
    }
    __syncthreads();
#pragma unroll
    for (int ks = 0; ks < 2; ++ks) {
      f16x8 a0 = *(const f16x8*)(As + (wm * 32 + lr) * 72 + ks * 32 + lk * 8);
      f16x8 a1 = *(const f16x8*)(As + (wm * 32 + 16 + lr) * 72 + ks * 32 + lk * 8);
      f16x8 b0 = *(const f16x8*)(Bs + (wn * 32 + lr) * 72 + ks * 32 + lk * 8);
      f16x8 b1 = *(const f16x8*)(Bs + (wn * 32 + 16 + lr) * 72 + ks * 32 + lk * 8);
      acc[0][0] = __builtin_amdgcn_mfma_f32_16x16x32_f16(a0, b0, acc[0][0], 0, 0, 0);
      acc[0][1] = __builtin_amdgcn_mfma_f32_16x16x32_f16(a0, b1, acc[0][1], 0, 0, 0);
      acc[1][0] = __builtin_amdgcn_mfma_f32_16x16x32_f16(a1, b0, acc[1][0], 0, 0, 0);
      acc[1][1] = __builtin_amdgcn_mfma_f32_16x16x32_f16(a1, b1, acc[1][1], 0, 0, 0);
    }
  }

#pragma unroll
  for (int mf = 0; mf < 2; ++mf)
#pragma unroll
    for (int nf = 0; nf < 2; ++nf) {
      int n = n0 + wn * 32 + nf * 16 + lr;
      float bias = fcb[n];
      int bbase = wm * 32 + mf * 16 + lk * 4;
#pragma unroll
      for (int rg = 0; rg < 4; ++rg)
        out[(size_t)(bbase + rg) * NCLS_ + n] = acc[mf][nf][rg] + bias;
    }
}

// ---------------- launch ----------------

extern "C" void kernel_launch(void* const* d_in, const int* in_sizes, int n_in,
                              void* d_out, int out_size, void* d_ws,
                              size_t ws_size, hipStream_t stream) {
  const int* tokens = (const int*)d_in[0];
  const float* emb = (const float*)d_in[1];
  const float* W_ih0 = (const float*)d_in[2];
  const float* W_hh0 = (const float*)d_in[3];
  const float* b_ih0 = (const float*)d_in[4];
  const float* b_hh0 = (const float*)d_in[5];
  const float* W_ih1 = (const float*)d_in[6];
  const float* W_hh1 = (const float*)d_in[7];
  const float* b_ih1 = (const float*)d_in[8];
  const float* b_hh1 = (const float*)d_in[9];
  const float* fc_w = (const float*)d_in[10];
  const float* fc_b = (const float*)d_in[11];
  float* out = (float*)d_out;

  char* ws = (char*)d_ws;
  size_t off = 0;
  auto carve = [&](size_t bytes) -> char* {
    char* p = ws + off;
    off += (bytes + 255) & ~(size_t)255;
    return p;
  };
  f16* w0i = (f16*)carve((size_t)G4_ * EMB_ * 2);
  f16* w0h = (f16*)carve((size_t)G4_ * HID_ * 2);
  f16* w1i = (f16*)carve((size_t)G4_ * HID_ * 2);
  f16* w1h = (f16*)carve((size_t)G4_ * HID_ * 2);
  f16* x0 = (f16*)carve((size_t)T_ * B_ * EMB_ * 2);
  float* b0s = (float*)carve(G4_ * 4);
  float* b1s = (float*)carve(G4_ * 4);
  f16* h0r = (f16*)carve(257ull * BH * 2);  // blocked: [t][slice][b][u8]
  f16* h1r = (f16*)carve(257ull * BH * 2);
  unsigned* flags = (unsigned*)carve(1024 * 4);  // 2 chains x 8 contiguous sectors

  hipMemsetAsync(flags, 0, 1024 * 4, stream);
  hipMemsetAsync(h0r, 0, (size_t)BH * 2, stream);
  hipMemsetAsync(h1r, 0, (size_t)BH * 2, stream);

  cvt_kernel<<<(G4_ * EMB_ / 4 + 255) / 256, 256, 0, stream>>>(W_ih0, w0i, G4_ * EMB_ / 4);
  cvt_kernel<<<(G4_ * HID_ / 4 + 255) / 256, 256, 0, stream>>>(W_hh0, w0h, G4_ * HID_ / 4);
  cvt_kernel<<<(G4_ * HID_ / 4 + 255) / 256, 256, 0, stream>>>(W_ih1, w1i, G4_ * HID_ / 4);
  cvt_kernel<<<(G4_ * HID_ / 4 + 255) / 256, 256, 0, stream>>>(W_hh1, w1h, G4_ * HID_ / 4);
  bsum_kernel<<<(G4_ + 255) / 256, 256, 0, stream>>>(b_ih0, b_hh0, b0s, b_ih1, b_hh1, b1s);
  gather_kernel<<<T_ * B_, 128, 0, stream>>>(tokens, emb, x0);

  persist_kernel<<<256, 512, 0, stream>>>(x0, w0i, w0h, w1i, w1h, b0s, b1s,
                                          h0r, h1r, flags);

  fc_kernel<<<NCLS_ / 64, 256, 0, stream>>>(h1r + 256ull * BH, fc_w, fc_b, out);
}